// Round 3
// baseline (919.872 us; speedup 1.0000x reference)
//
#include <hip/hip_runtime.h>

#define N_ROWS 400000
#define DIM 256
#define NCLS 1000
#define NSQ 10
#define NB 256
#define NT 512
#define NWAVE (NT/64)      // 8 waves/block
#define TOTW (NB*NWAVE)    // 2048 waves total

// ---- workspace layout (bytes) ----
#define OFF_BAR     0
#define OFF_COUNTS  1024              // 1024 u32
#define OFF_COLSUM  5120              // 256 f32
#define OFF_MAXBUF  6144              // 16 u32
#define ZERO_BYTES  6208
#define OFF_BASE    6208              // 1024 u32
#define OFF_CURSOR  10304             // 1024 u32
#define OFF_V       14400             // 256 f32
#define OFF_IDX     15424             // 400000 u32
#define OFF_NC      1615424           // [NCLS][DIM] f32
#define OFF_MA      2639424           // 256 KB
#define OFF_MB      2901568           // 256 KB

// device-scope grid barrier: monotonic counter, agent-scope atomics.
// bar is zeroed by the memset at the head of every kernel_launch call.
__device__ __forceinline__ void grid_bar(unsigned* bar, int& phase) {
  __syncthreads();
  if (threadIdx.x == 0) {
    ++phase;
    __threadfence();                                   // release our writes (L2 wb)
    __hip_atomic_fetch_add(bar, 1u, __ATOMIC_RELEASE, __HIP_MEMORY_SCOPE_AGENT);
    const unsigned target = (unsigned)NB * (unsigned)phase;
    while (__hip_atomic_load(bar, __ATOMIC_ACQUIRE, __HIP_MEMORY_SCOPE_AGENT) < target)
      __builtin_amdgcn_s_sleep(2);
    __threadfence();                                   // acquire others' writes
  }
  __syncthreads();
}

__global__ __launch_bounds__(NT) void k_mono(const float* __restrict__ grads,
                                             const int* __restrict__ labels,
                                             const float* __restrict__ centroids,
                                             float* __restrict__ out,
                                             char* __restrict__ ws) {
  unsigned* bar     = (unsigned*)(ws + OFF_BAR);
  unsigned* counts  = (unsigned*)(ws + OFF_COUNTS);
  float*    colsum  = (float*)(ws + OFF_COLSUM);
  unsigned* maxbuf  = (unsigned*)(ws + OFF_MAXBUF);
  unsigned* base    = (unsigned*)(ws + OFF_BASE);
  unsigned* cursor  = (unsigned*)(ws + OFF_CURSOR);
  float*    vfin    = (float*)(ws + OFF_V);
  unsigned* idx     = (unsigned*)(ws + OFF_IDX);
  float*    NC      = (float*)(ws + OFF_NC);
  float*    MA      = (float*)(ws + OFF_MA);
  float*    MB      = (float*)(ws + OFF_MB);

  __shared__ __align__(16) float sf[2048];             // 8 KB, aliased per phase
  unsigned* su = (unsigned*)sf;

  const int t = threadIdx.x;
  const int b = blockIdx.x;
  int phase = 0;

  // ---- P1: label histogram (LDS-private, then global atomics) ----
  for (int i = t; i < NCLS; i += NT) su[i] = 0u;
  __syncthreads();
  for (int i = b*NT + t; i < N_ROWS; i += NB*NT)
    atomicAdd(&su[labels[i]], 1u);
  __syncthreads();
  for (int i = t; i < NCLS; i += NT) { unsigned v = su[i]; if (v) atomicAdd(&counts[i], v); }
  grid_bar(bar, phase);

  // ---- P2: exclusive scan of counts (block 0, Blelloch over 1024) ----
  if (b == 0) {
    su[t] = counts[t]; su[t+512] = counts[t+512];      // [1000..1023] are zero
    int offset = 1;
    for (int d = 512; d > 0; d >>= 1) {
      __syncthreads();
      if (t < d) { int ai = offset*(2*t+1)-1, bi = offset*(2*t+2)-1; su[bi] += su[ai]; }
      offset <<= 1;
    }
    __syncthreads();
    if (t == 0) su[1023] = 0u;
    for (int d = 1; d < 1024; d <<= 1) {
      offset >>= 1;
      __syncthreads();
      if (t < d) { int ai = offset*(2*t+1)-1, bi = offset*(2*t+2)-1;
                   unsigned tm = su[ai]; su[ai] = su[bi]; su[bi] += tm; }
    }
    __syncthreads();
    base[t] = su[t]; cursor[t] = su[t];
    base[t+512] = su[t+512]; cursor[t+512] = su[t+512];
  }
  grid_bar(bar, phase);

  // ---- P3: scatter row indices into class-sorted order ----
  for (int i = b*NT + t; i < N_ROWS; i += NB*NT) {
    unsigned p = atomicAdd(&cursor[labels[i]], 1u);
    idx[p] = (unsigned)i;
  }
  grid_bar(bar, phase);

  // ---- P4: per-class gather-mean + EMA -> NC ----
  {
    const float4* g4 = (const float4*)grads;
    const int wave = t >> 6, lane = t & 63;
    for (int cls = b; cls < NCLS; cls += NB) {
      unsigned s0 = base[cls], n = counts[cls];
      float4 acc = make_float4(0.f, 0.f, 0.f, 0.f);
      unsigned u = (unsigned)wave;
      for (; u + 8 < n; u += 16) {                     // 2 rows in flight per wave
        unsigned r0 = idx[s0+u], r1 = idx[s0+u+8];
        float4 a = g4[(size_t)r0*64 + lane];
        float4 c2 = g4[(size_t)r1*64 + lane];
        acc.x += a.x + c2.x; acc.y += a.y + c2.y;
        acc.z += a.z + c2.z; acc.w += a.w + c2.w;
      }
      for (; u < n; u += 8) {
        unsigned r0 = idx[s0+u];
        float4 a = g4[(size_t)r0*64 + lane];
        acc.x += a.x; acc.y += a.y; acc.z += a.z; acc.w += a.w;
      }
      __syncthreads();                                 // smem reuse guard
      ((float4*)sf)[wave*64 + lane] = acc;             // [8][256] floats
      __syncthreads();
      if (t < DIM) {
        float s = 0.f;
        #pragma unroll
        for (int w2 = 0; w2 < NWAVE; ++w2) s += sf[w2*256 + t];
        float mean = s / fmaxf((float)n, 1.0f);
        float ce = centroids[cls*DIM + t];
        NC[cls*DIM + t] = (n > 0u) ? (0.9f*ce + 0.1f*mean) : ce;
      }
    }
  }
  grid_bar(bar, phase);

  // ---- P5: column sums of NC ----
  if (t < DIM) {
    float s = 0.f;
    for (int cls = b; cls < NCLS; cls += NB) s += NC[cls*DIM + t];
    atomicAdd(&colsum[t], s);
  }
  grid_bar(bar, phase);

  // ---- P6: Gram of centered NC (block b = column b) + max|.| ----
  {
    const int i = t & 255, h = t >> 8;
    float acc = 0.f;
    for (int k = h*500; k < h*500 + 500; ++k)
      acc += NC[k*DIM + i] * NC[k*DIM + b];
    sf[t] = acc;
    __syncthreads();
    float aval = 0.f;
    if (h == 0) {
      float val = sf[i] + sf[i+256] - colsum[i]*colsum[b]*(1.0f/NCLS);
      MA[b*DIM + i] = val;
      aval = fabsf(val);
    }
    __syncthreads();
    sf[t] = aval;
    __syncthreads();
    for (int srd = 256; srd > 0; srd >>= 1) {
      if (t < srd) sf[t] = fmaxf(sf[t], sf[t+srd]);
      __syncthreads();
    }
    if (t == 0) atomicMax(maxbuf, __float_as_uint(sf[0]));
  }
  grid_bar(bar, phase);

  // ---- P7: NSQ normalized squarings (block b = column b of C) ----
  for (int st = 0; st < NSQ; ++st) {
    const float* A = (st & 1) ? MB : MA;
    float*       C = (st & 1) ? MA : MB;
    const int i = t & 255, h = t >> 8;
    const float inv = 1.0f / __uint_as_float(maxbuf[st]);
    if (t < DIM) sf[1024 + t] = A[b*DIM + t];          // row b == column b (symmetric)
    __syncthreads();
    float acc = 0.f;
    #pragma unroll 8
    for (int k = h*128; k < h*128 + 128; ++k)
      acc += A[k*DIM + i] * sf[1024 + k];
    sf[t] = acc;
    __syncthreads();
    float aval = 0.f;
    if (h == 0) {
      float val = (sf[i] + sf[i+256]) * inv * inv;
      C[b*DIM + i] = val;
      aval = fabsf(val);
    }
    __syncthreads();
    sf[t] = aval;
    __syncthreads();
    for (int srd = 256; srd > 0; srd >>= 1) {
      if (t < srd) sf[t] = fmaxf(sf[t], sf[t+srd]);
      __syncthreads();
    }
    if (t == 0) atomicMax(&maxbuf[st+1], __float_as_uint(sf[0]));
    grid_bar(bar, phase);
  }
  // NSQ even -> final matrix in MA

  // ---- P8: eigen finish entirely in block 0 (no grid barriers inside) ----
  if (b == 0) {
    const int i = t & 255, h = t >> 8;
    float ns = 0.f;
    if (t < DIM)
      for (int k = 0; k < DIM; ++k) { float x = MA[k*DIM + t]; ns += x*x; }
    float* val = sf; int* vid = (int*)(sf + 256);
    if (t < DIM) { val[t] = ns; vid[t] = t; }
    __syncthreads();
    for (int srd = 128; srd > 0; srd >>= 1) {
      if (t < srd && val[t+srd] > val[t]) { val[t] = val[t+srd]; vid[t] = vid[t+srd]; }
      __syncthreads();
    }
    const int jm = vid[0];
    const float nrm = sqrtf(fmaxf(val[0], 1e-30f));
    __syncthreads();
    float* xv = sf + 512; float* yv = sf + 768;
    if (t < DIM) xv[t] = MA[(size_t)jm*DIM + t] / nrm;
    __syncthreads();
    for (int it = 0; it < 3; ++it) {                   // power-iteration polish in LDS
      float a2 = 0.f;
      for (int k = h*128; k < h*128 + 128; ++k)
        a2 += MA[k*DIM + i] * xv[k];                   // symmetric -> coalesced
      sf[t] = a2;
      __syncthreads();
      if (h == 0) yv[i] = sf[i] + sf[i+256];
      __syncthreads();
      float q = (t < DIM) ? yv[t]*yv[t] : 0.f;
      sf[t] = q;
      __syncthreads();
      for (int srd = 256; srd > 0; srd >>= 1) {
        if (t < srd) sf[t] += sf[t+srd];
        __syncthreads();
      }
      const float innrm = rsqrtf(fmaxf(sf[0], 1e-30f));
      __syncthreads();
      if (t < DIM) xv[t] = yv[t] * innrm;
      __syncthreads();
    }
    if (t < DIM) vfin[t] = xv[t];
  }
  grid_bar(bar, phase);

  // ---- P9: projection out = g - (g.v) v ----
  {
    const int lane2 = t & 63;
    const float4 v4 = ((const float4*)vfin)[lane2];
    const int w = b*NWAVE + (t >> 6);
    const float4* gg = (const float4*)grads;
    float4* o4 = (float4*)out;
    int r = w;
    for (; r + TOTW < N_ROWS; r += 2*TOTW) {           // 2 rows in flight
      float4 a = gg[(size_t)r*64 + lane2];
      float4 c2 = gg[(size_t)(r+TOTW)*64 + lane2];
      float da = a.x*v4.x + a.y*v4.y + a.z*v4.z + a.w*v4.w;
      float db = c2.x*v4.x + c2.y*v4.y + c2.z*v4.z + c2.w*v4.w;
      #pragma unroll
      for (int m = 1; m < 64; m <<= 1) { da += __shfl_xor(da, m, 64); db += __shfl_xor(db, m, 64); }
      o4[(size_t)r*64 + lane2] = make_float4(a.x-da*v4.x, a.y-da*v4.y, a.z-da*v4.z, a.w-da*v4.w);
      o4[(size_t)(r+TOTW)*64 + lane2] = make_float4(c2.x-db*v4.x, c2.y-db*v4.y, c2.z-db*v4.z, c2.w-db*v4.w);
    }
    for (; r < N_ROWS; r += TOTW) {
      float4 a = gg[(size_t)r*64 + lane2];
      float da = a.x*v4.x + a.y*v4.y + a.z*v4.z + a.w*v4.w;
      #pragma unroll
      for (int m = 1; m < 64; m <<= 1) da += __shfl_xor(da, m, 64);
      o4[(size_t)r*64 + lane2] = make_float4(a.x-da*v4.x, a.y-da*v4.y, a.z-da*v4.z, a.w-da*v4.w);
    }
  }
}

extern "C" void kernel_launch(void* const* d_in, const int* in_sizes, int n_in,
                              void* d_out, int out_size, void* d_ws, size_t ws_size,
                              hipStream_t stream) {
  const float* grads     = (const float*)d_in[0];
  const int*   labels    = (const int*)d_in[1];
  const float* centroids = (const float*)d_in[2];
  float* out = (float*)d_out;
  char* ws = (char*)d_ws;

  // zero barrier counter + atomic targets every call (graph-replay safe)
  hipMemsetAsync(ws, 0, ZERO_BYTES, stream);

  k_mono<<<NB, NT, 0, stream>>>(grads, labels, centroids, out, ws);
}

// Round 4
// 725.357 us; speedup vs baseline: 1.2682x; 1.2682x over previous
//
#include <hip/hip_runtime.h>

#define N_ROWS 400000
#define DIM 256
#define NCLS 1000
#define NSQ 10

#define NB_S 256      // k_sort blocks
#define NT_S 512
#define NBE  128      // k_eigen blocks
#define NTE  256
#define NB_P 2048     // k_project blocks
#define NT_P 256
#define TOTW_P (NB_P * (NT_P / 64))   // 8192 waves

// ---- workspace layout (bytes) ----
#define OFF_BAR     0                 // k_sort barrier counter
#define OFF_BAR2    64                // k_eigen barrier counter
#define OFF_COUNTS  1024              // 1024 u32
#define OFF_COLSUM  5120              // 256 f32
#define OFF_MAXBUF  6144              // 16 u32
#define ZERO_BYTES  6208
#define OFF_BASE    6208              // 1024 u32
#define OFF_CURSOR  10304             // 1024 u32
#define OFF_V       14400             // 256 f32
#define OFF_IDX     15424             // 400000 u32
#define OFF_NC      1615424           // [NCLS][DIM] f32
#define OFF_MA      2639424           // 256 KB
#define OFF_MB      2901568           // 256 KB

// device-scope grid barrier: monotonic counter, agent-scope atomics.
// counter zeroed by the memset at the head of every kernel_launch call.
template <int NBLK>
__device__ __forceinline__ void grid_bar(unsigned* bar, int& phase) {
  __syncthreads();
  if (threadIdx.x == 0) {
    ++phase;
    __threadfence();
    __hip_atomic_fetch_add(bar, 1u, __ATOMIC_RELEASE, __HIP_MEMORY_SCOPE_AGENT);
    const unsigned target = (unsigned)NBLK * (unsigned)phase;
    while (__hip_atomic_load(bar, __ATOMIC_ACQUIRE, __HIP_MEMORY_SCOPE_AGENT) < target)
      __builtin_amdgcn_s_sleep(2);
    __threadfence();
  }
  __syncthreads();
}

// ---------- counting sort of row indices (hist -> scan -> scatter) ----------
__global__ __launch_bounds__(NT_S) void k_sort(const int* __restrict__ labels,
                                               char* __restrict__ ws) {
  unsigned* bar    = (unsigned*)(ws + OFF_BAR);
  unsigned* counts = (unsigned*)(ws + OFF_COUNTS);
  unsigned* base   = (unsigned*)(ws + OFF_BASE);
  unsigned* cursor = (unsigned*)(ws + OFF_CURSOR);
  unsigned* idx    = (unsigned*)(ws + OFF_IDX);

  __shared__ unsigned su[1024];
  const int t = threadIdx.x, b = blockIdx.x;
  int phase = 0;

  // P1: histogram (LDS-private, flush to global)
  for (int i = t; i < NCLS; i += NT_S) su[i] = 0u;
  __syncthreads();
  for (int i = b*NT_S + t; i < N_ROWS; i += NB_S*NT_S)
    atomicAdd(&su[labels[i]], 1u);
  __syncthreads();
  for (int i = t; i < NCLS; i += NT_S) { unsigned v = su[i]; if (v) atomicAdd(&counts[i], v); }
  grid_bar<NB_S>(bar, phase);

  // P2: exclusive scan (block 0, Blelloch over 1024)
  if (b == 0) {
    su[t] = counts[t]; su[t+512] = counts[t+512];
    int offset = 1;
    for (int d = 512; d > 0; d >>= 1) {
      __syncthreads();
      if (t < d) { int ai = offset*(2*t+1)-1, bi = offset*(2*t+2)-1; su[bi] += su[ai]; }
      offset <<= 1;
    }
    __syncthreads();
    if (t == 0) su[1023] = 0u;
    for (int d = 1; d < 1024; d <<= 1) {
      offset >>= 1;
      __syncthreads();
      if (t < d) { int ai = offset*(2*t+1)-1, bi = offset*(2*t+2)-1;
                   unsigned tm = su[ai]; su[ai] = su[bi]; su[bi] += tm; }
    }
    __syncthreads();
    base[t] = su[t]; cursor[t] = su[t];
    base[t+512] = su[t+512]; cursor[t+512] = su[t+512];
  }
  grid_bar<NB_S>(bar, phase);

  // P3: scatter
  for (int i = b*NT_S + t; i < N_ROWS; i += NB_S*NT_S) {
    unsigned p = atomicAdd(&cursor[labels[i]], 1u);
    idx[p] = (unsigned)i;
  }
}

// ---------- per-class gather-mean + EMA -> NC (1000 blocks x 512) ----------
__global__ __launch_bounds__(512) void k_reduce(const float* __restrict__ grads,
                                                const unsigned* __restrict__ idx,
                                                const unsigned* __restrict__ base,
                                                const unsigned* __restrict__ counts,
                                                const float* __restrict__ centroids,
                                                float* __restrict__ NC) {
  const int cls = blockIdx.x;
  const unsigned s0 = base[cls], n = counts[cls];
  const int wave = threadIdx.x >> 6, lane = threadIdx.x & 63;
  const float4* g4 = (const float4*)grads;
  float4 acc = make_float4(0.f, 0.f, 0.f, 0.f);
  unsigned u = (unsigned)wave;
  for (; u + 8 < n; u += 16) {                 // 2 rows in flight per wave
    unsigned r0 = idx[s0+u], r1 = idx[s0+u+8];
    float4 a = g4[(size_t)r0*64 + lane];
    float4 c = g4[(size_t)r1*64 + lane];
    acc.x += a.x + c.x; acc.y += a.y + c.y;
    acc.z += a.z + c.z; acc.w += a.w + c.w;
  }
  for (; u < n; u += 8) {
    unsigned r0 = idx[s0+u];
    float4 a = g4[(size_t)r0*64 + lane];
    acc.x += a.x; acc.y += a.y; acc.z += a.z; acc.w += a.w;
  }
  __shared__ float4 tmp[8][64];
  tmp[wave][lane] = acc;
  __syncthreads();
  const int d = threadIdx.x;
  if (d < DIM) {
    const float* tf = (const float*)tmp;
    float s = 0.f;
    #pragma unroll
    for (int w2 = 0; w2 < 8; ++w2) s += tf[w2*256 + d];
    float mean = s / fmaxf((float)n, 1.0f);
    float ce = centroids[cls*DIM + d];
    NC[cls*DIM + d] = (n > 0u) ? (0.9f*ce + 0.1f*mean) : ce;
  }
}

// ---------- eigenvector chain (coop 128 x 256, 12 grid barriers) ----------
__global__ __launch_bounds__(NTE) void k_eigen(char* __restrict__ ws) {
  unsigned* bar2   = (unsigned*)(ws + OFF_BAR2);
  float*    colsum = (float*)(ws + OFF_COLSUM);
  unsigned* maxbuf = (unsigned*)(ws + OFF_MAXBUF);
  float*    vfin   = (float*)(ws + OFF_V);
  float*    NC     = (float*)(ws + OFF_NC);
  float*    MA     = (float*)(ws + OFF_MA);
  float*    MB     = (float*)(ws + OFF_MB);

  __shared__ float scol[NCLS];       // staged column / arow
  __shared__ float sred[NTE];
  __shared__ int   sidx[NTE];
  __shared__ float sx[DIM], sy[DIM];

  const int t = threadIdx.x, b = blockIdx.x;
  int phase = 0;

  // P1: column sums of NC
  {
    float s = 0.f;
    for (int cls = b; cls < NCLS; cls += NBE) s += NC[cls*DIM + t];
    atomicAdd(&colsum[t], s);
  }
  grid_bar<NBE>(bar2, phase);

  // P2: Gram of centered NC (2 columns/block) + max|.|
  {
    float lmax = 0.f;
    for (int q = 0; q < 2; ++q) {
      const int j = b + NBE*q;
      for (int k = t; k < NCLS; k += NTE) scol[k] = NC[k*DIM + j];
      __syncthreads();
      float acc = 0.f;
      for (int k = 0; k < NCLS; ++k) acc += NC[k*DIM + t] * scol[k];
      float val = acc - colsum[t]*colsum[j]*(1.0f/NCLS);
      MA[j*DIM + t] = val;
      lmax = fmaxf(lmax, fabsf(val));
      __syncthreads();
    }
    sred[t] = lmax;
    __syncthreads();
    for (int s = NTE/2; s > 0; s >>= 1) {
      if (t < s) sred[t] = fmaxf(sred[t], sred[t+s]);
      __syncthreads();
    }
    if (t == 0) atomicMax(maxbuf, __float_as_uint(sred[0]));
  }
  grid_bar<NBE>(bar2, phase);

  // P3: NSQ normalized squarings
  for (int st = 0; st < NSQ; ++st) {
    const float* A = (st & 1) ? MB : MA;
    float*       C = (st & 1) ? MA : MB;
    const float inv = 1.0f / __uint_as_float(maxbuf[st]);
    float lmax = 0.f;
    for (int q = 0; q < 2; ++q) {
      const int j = b + NBE*q;
      scol[t] = A[j*DIM + t];            // row j == column j (symmetric)
      __syncthreads();
      float acc = 0.f;
      #pragma unroll 8
      for (int k = 0; k < DIM; ++k) acc += A[k*DIM + t] * scol[k];
      float val = acc * inv * inv;
      C[j*DIM + t] = val;
      lmax = fmaxf(lmax, fabsf(val));
      __syncthreads();
    }
    sred[t] = lmax;
    __syncthreads();
    for (int s = NTE/2; s > 0; s >>= 1) {
      if (t < s) sred[t] = fmaxf(sred[t], sred[t+s]);
      __syncthreads();
    }
    if (t == 0) atomicMax(&maxbuf[st+1], __float_as_uint(sred[0]));
    grid_bar<NBE>(bar2, phase);
  }
  // NSQ even -> final matrix in MA

  // P4: pickcol + 3 power-polish iterations, block 0 only
  if (b == 0) {
    float ns = 0.f;
    for (int k = 0; k < DIM; ++k) { float x = MA[k*DIM + t]; ns += x*x; }
    sred[t] = ns; sidx[t] = t;
    __syncthreads();
    for (int s = 128; s > 0; s >>= 1) {
      if (t < s && sred[t+s] > sred[t]) { sred[t] = sred[t+s]; sidx[t] = sidx[t+s]; }
      __syncthreads();
    }
    const int jm = sidx[0];
    const float nrm = sqrtf(fmaxf(sred[0], 1e-30f));
    __syncthreads();
    sx[t] = MA[(size_t)jm*DIM + t] / nrm;
    __syncthreads();
    for (int it = 0; it < 3; ++it) {
      float a2 = 0.f;
      for (int k = 0; k < DIM; ++k) a2 += MA[k*DIM + t] * sx[k];   // symmetric
      sy[t] = a2;
      sred[t] = a2*a2;
      __syncthreads();
      for (int s = 128; s > 0; s >>= 1) {
        if (t < s) sred[t] += sred[t+s];
        __syncthreads();
      }
      const float innrm = rsqrtf(fmaxf(sred[0], 1e-30f));
      __syncthreads();
      sx[t] = sy[t] * innrm;
      __syncthreads();
    }
    vfin[t] = sx[t];
  }
}

// ---------- projection out = g - (g.v) v (2048 x 256, 2-deep) ----------
__global__ __launch_bounds__(NT_P) void k_project(const float4* __restrict__ g4,
                                                  const float* __restrict__ v,
                                                  float4* __restrict__ out) {
  const int lane = threadIdx.x & 63;
  const float4 v4 = ((const float4*)v)[lane];
  const int w = blockIdx.x * (NT_P/64) + (threadIdx.x >> 6);
  int r = w;
  for (; r + TOTW_P < N_ROWS; r += 2*TOTW_P) {
    float4 a = g4[(size_t)r*64 + lane];
    float4 c = g4[(size_t)(r+TOTW_P)*64 + lane];
    float da = a.x*v4.x + a.y*v4.y + a.z*v4.z + a.w*v4.w;
    float db = c.x*v4.x + c.y*v4.y + c.z*v4.z + c.w*v4.w;
    #pragma unroll
    for (int m = 1; m < 64; m <<= 1) { da += __shfl_xor(da, m, 64); db += __shfl_xor(db, m, 64); }
    out[(size_t)r*64 + lane] = make_float4(a.x-da*v4.x, a.y-da*v4.y, a.z-da*v4.z, a.w-da*v4.w);
    out[(size_t)(r+TOTW_P)*64 + lane] = make_float4(c.x-db*v4.x, c.y-db*v4.y, c.z-db*v4.z, c.w-db*v4.w);
  }
  for (; r < N_ROWS; r += TOTW_P) {
    float4 a = g4[(size_t)r*64 + lane];
    float da = a.x*v4.x + a.y*v4.y + a.z*v4.z + a.w*v4.w;
    #pragma unroll
    for (int m = 1; m < 64; m <<= 1) da += __shfl_xor(da, m, 64);
    out[(size_t)r*64 + lane] = make_float4(a.x-da*v4.x, a.y-da*v4.y, a.z-da*v4.z, a.w-da*v4.w);
  }
}

extern "C" void kernel_launch(void* const* d_in, const int* in_sizes, int n_in,
                              void* d_out, int out_size, void* d_ws, size_t ws_size,
                              hipStream_t stream) {
  const float* grads     = (const float*)d_in[0];
  const int*   labels    = (const int*)d_in[1];
  const float* centroids = (const float*)d_in[2];
  float* out = (float*)d_out;
  char* ws = (char*)d_ws;

  unsigned* idx    = (unsigned*)(ws + OFF_IDX);
  unsigned* counts = (unsigned*)(ws + OFF_COUNTS);
  unsigned* base   = (unsigned*)(ws + OFF_BASE);
  float*    vfin   = (float*)(ws + OFF_V);
  float*    NC     = (float*)(ws + OFF_NC);

  // zero barrier counters + atomic targets every call (graph-replay safe)
  hipMemsetAsync(ws, 0, ZERO_BYTES, stream);

  k_sort<<<NB_S, NT_S, 0, stream>>>(labels, ws);
  k_reduce<<<NCLS, 512, 0, stream>>>(grads, idx, base, counts, centroids, NC);
  k_eigen<<<NBE, NTE, 0, stream>>>(ws);
  k_project<<<NB_P, NT_P, 0, stream>>>((const float4*)grads, vfin, (float4*)out);
}

// Round 5
// 684.477 us; speedup vs baseline: 1.3439x; 1.0597x over previous
//
#include <hip/hip_runtime.h>

#define N_ROWS 400000
#define DIM 256
#define NCLS 1000
#define NSQ 10

#define NB_S 256      // k_sort blocks
#define NT_S 512
#define NBE  256      // k_eigen blocks (one Gram column each)
#define NTE  1024
#define NB_P 2048     // k_project blocks
#define NT_P 256
#define TOTW_P (NB_P * (NT_P / 64))   // 8192 waves

// ---- workspace layout (bytes) ----
#define OFF_BAR     0                 // k_sort barrier counter
#define OFF_BAR2    64                // k_eigen barrier counter
#define OFF_COUNTS  1024              // 1024 u32
#define OFF_COLSUM  5120              // 256 f32
#define OFF_MAXBUF  6144              // 16 u32
#define ZERO_BYTES  6208
#define OFF_BASE    6208              // 1024 u32
#define OFF_CURSOR  10304             // 1024 u32
#define OFF_V       14400             // 256 f32
#define OFF_IDX     15424             // 400000 u32
#define OFF_NC      1615424           // [NCLS][DIM] f32
#define OFF_MA      2639424           // 256 KB
#define OFF_MB      2901568           // 256 KB

// device-scope grid barrier: monotonic counter, agent-scope atomics.
// counter zeroed by the memset at the head of every kernel_launch call.
template <int NBLK>
__device__ __forceinline__ void grid_bar(unsigned* bar, int& phase) {
  __syncthreads();
  if (threadIdx.x == 0) {
    ++phase;
    __threadfence();
    __hip_atomic_fetch_add(bar, 1u, __ATOMIC_RELEASE, __HIP_MEMORY_SCOPE_AGENT);
    const unsigned target = (unsigned)NBLK * (unsigned)phase;
    while (__hip_atomic_load(bar, __ATOMIC_ACQUIRE, __HIP_MEMORY_SCOPE_AGENT) < target)
      __builtin_amdgcn_s_sleep(2);
    __threadfence();
  }
  __syncthreads();
}

// ---------- counting sort of row indices (hist -> scan -> scatter) ----------
__global__ __launch_bounds__(NT_S) void k_sort(const int* __restrict__ labels,
                                               char* __restrict__ ws) {
  unsigned* bar    = (unsigned*)(ws + OFF_BAR);
  unsigned* counts = (unsigned*)(ws + OFF_COUNTS);
  unsigned* base   = (unsigned*)(ws + OFF_BASE);
  unsigned* cursor = (unsigned*)(ws + OFF_CURSOR);
  unsigned* idx    = (unsigned*)(ws + OFF_IDX);

  __shared__ unsigned su[1024];
  const int t = threadIdx.x, b = blockIdx.x;
  int phase = 0;

  // P1: histogram (LDS-private, flush to global)
  for (int i = t; i < NCLS; i += NT_S) su[i] = 0u;
  __syncthreads();
  for (int i = b*NT_S + t; i < N_ROWS; i += NB_S*NT_S)
    atomicAdd(&su[labels[i]], 1u);
  __syncthreads();
  for (int i = t; i < NCLS; i += NT_S) { unsigned v = su[i]; if (v) atomicAdd(&counts[i], v); }
  grid_bar<NB_S>(bar, phase);

  // P2: exclusive scan (block 0, Blelloch over 1024)
  if (b == 0) {
    su[t] = counts[t]; su[t+512] = counts[t+512];
    int offset = 1;
    for (int d = 512; d > 0; d >>= 1) {
      __syncthreads();
      if (t < d) { int ai = offset*(2*t+1)-1, bi = offset*(2*t+2)-1; su[bi] += su[ai]; }
      offset <<= 1;
    }
    __syncthreads();
    if (t == 0) su[1023] = 0u;
    for (int d = 1; d < 1024; d <<= 1) {
      offset >>= 1;
      __syncthreads();
      if (t < d) { int ai = offset*(2*t+1)-1, bi = offset*(2*t+2)-1;
                   unsigned tm = su[ai]; su[ai] = su[bi]; su[bi] += tm; }
    }
    __syncthreads();
    base[t] = su[t]; cursor[t] = su[t];
    base[t+512] = su[t+512]; cursor[t+512] = su[t+512];
  }
  grid_bar<NB_S>(bar, phase);

  // P3: scatter
  for (int i = b*NT_S + t; i < N_ROWS; i += NB_S*NT_S) {
    unsigned p = atomicAdd(&cursor[labels[i]], 1u);
    idx[p] = (unsigned)i;
  }
}

// ---------- per-class gather-mean + EMA -> NC (+ colsum fold) ----------
__global__ __launch_bounds__(512) void k_reduce(const float* __restrict__ grads,
                                                const unsigned* __restrict__ idx,
                                                const unsigned* __restrict__ base,
                                                const unsigned* __restrict__ counts,
                                                const float* __restrict__ centroids,
                                                float* __restrict__ NC,
                                                float* __restrict__ colsum) {
  const int cls = blockIdx.x;
  const unsigned s0 = base[cls], n = counts[cls];
  const int wave = threadIdx.x >> 6, lane = threadIdx.x & 63;
  const float4* g4 = (const float4*)grads;
  float4 acc = make_float4(0.f, 0.f, 0.f, 0.f);
  unsigned u = (unsigned)wave;
  for (; u + 8 < n; u += 16) {                 // 2 rows in flight per wave
    unsigned r0 = idx[s0+u], r1 = idx[s0+u+8];
    float4 a = g4[(size_t)r0*64 + lane];
    float4 c = g4[(size_t)r1*64 + lane];
    acc.x += a.x + c.x; acc.y += a.y + c.y;
    acc.z += a.z + c.z; acc.w += a.w + c.w;
  }
  for (; u < n; u += 8) {
    unsigned r0 = idx[s0+u];
    float4 a = g4[(size_t)r0*64 + lane];
    acc.x += a.x; acc.y += a.y; acc.z += a.z; acc.w += a.w;
  }
  __shared__ float4 tmp[8][64];
  tmp[wave][lane] = acc;
  __syncthreads();
  const int d = threadIdx.x;
  if (d < DIM) {
    const float* tf = (const float*)tmp;
    float s = 0.f;
    #pragma unroll
    for (int w2 = 0; w2 < 8; ++w2) s += tf[w2*256 + d];
    float mean = s / fmaxf((float)n, 1.0f);
    float ce = centroids[cls*DIM + d];
    float ncv = (n > 0u) ? (0.9f*ce + 0.1f*mean) : ce;
    NC[cls*DIM + d] = ncv;
    atomicAdd(&colsum[d], ncv);              // colsum folded here
  }
}

// ---------- eigenvector chain (coop 256 x 1024, 11 grid barriers) ----------
__global__ __launch_bounds__(NTE) void k_eigen(char* __restrict__ ws) {
  unsigned* bar2   = (unsigned*)(ws + OFF_BAR2);
  float*    colsum = (float*)(ws + OFF_COLSUM);
  unsigned* maxbuf = (unsigned*)(ws + OFF_MAXBUF);
  float*    vfin   = (float*)(ws + OFF_V);
  float*    NC     = (float*)(ws + OFF_NC);
  float*    MA     = (float*)(ws + OFF_MA);
  float*    MB     = (float*)(ws + OFF_MB);

  __shared__ float scol[NCLS];       // staged column (Gram) / row (squarings)
  __shared__ float sf[NTE];
  __shared__ int   sidx[256];
  __shared__ float sx[DIM], sy[DIM];

  const int t = threadIdx.x, b = blockIdx.x;
  const int i = t & 255, h = t >> 8;           // output row, k-chunk
  int phase = 0;

  // P1: Gram of centered NC, column j = b. 4-way k-split, deep unroll.
  {
    if (t < NCLS) scol[t] = NC[t*DIM + b];     // column gather (L2)
    __syncthreads();
    float acc = 0.f;
    const int k0 = h * 250;
    #pragma unroll 10
    for (int k = k0; k < k0 + 250; ++k)
      acc += NC[k*DIM + i] * scol[k];
    sf[t] = acc;
    __syncthreads();
    float aval = 0.f;
    if (h == 0) {
      float val = sf[i] + sf[i+256] + sf[i+512] + sf[i+768]
                - colsum[i]*colsum[b]*(1.0f/NCLS);
      MA[b*DIM + i] = val;
      aval = fabsf(val);
    }
    __syncthreads();
    sf[t] = aval;
    __syncthreads();
    for (int s = 512; s > 0; s >>= 1) {
      if (t < s) sf[t] = fmaxf(sf[t], sf[t+s]);
      __syncthreads();
    }
    if (t == 0) atomicMax(maxbuf, __float_as_uint(sf[0]));
  }
  grid_bar<NBE>(bar2, phase);

  // P2: NSQ normalized squarings, column j = b each step
  for (int st = 0; st < NSQ; ++st) {
    const float* A = (st & 1) ? MB : MA;
    float*       C = (st & 1) ? MA : MB;
    const float inv = 1.0f / __uint_as_float(maxbuf[st]);
    if (t < DIM) scol[t] = A[b*DIM + t];       // row b == column b (symmetric)
    __syncthreads();
    float acc = 0.f;
    const int k0 = h * 64;
    #pragma unroll 8
    for (int k = k0; k < k0 + 64; ++k)
      acc += A[k*DIM + i] * scol[k];
    sf[t] = acc;
    __syncthreads();
    float aval = 0.f;
    if (h == 0) {
      float val = (sf[i] + sf[i+256] + sf[i+512] + sf[i+768]) * inv * inv;
      C[b*DIM + i] = val;
      aval = fabsf(val);
    }
    __syncthreads();
    sf[t] = aval;
    __syncthreads();
    for (int s = 512; s > 0; s >>= 1) {
      if (t < s) sf[t] = fmaxf(sf[t], sf[t+s]);
      __syncthreads();
    }
    if (t == 0) atomicMax(&maxbuf[st+1], __float_as_uint(sf[0]));
    grid_bar<NBE>(bar2, phase);
  }
  // NSQ even -> final matrix in MA

  // P3: pickcol + 3 power-polish iterations, block 0 only
  if (b == 0) {
    float ns = 0.f;
    if (t < DIM) {
      #pragma unroll 8
      for (int k = 0; k < DIM; ++k) { float x = MA[k*DIM + t]; ns += x*x; }
      sf[t] = ns; sidx[t] = t;
    }
    __syncthreads();
    if (t < 128) {
      for (int s = 128; s > 0; s >>= 1) {
        if (t < s && sf[t+s] > sf[t]) { sf[t] = sf[t+s]; sidx[t] = sidx[t+s]; }
        __syncthreads();
      }
    } else {
      for (int s = 128; s > 0; s >>= 1) __syncthreads();
    }
    const int jm = sidx[0];
    const float nrm = sqrtf(fmaxf(sf[0], 1e-30f));
    __syncthreads();
    if (t < DIM) sx[t] = MA[(size_t)jm*DIM + t] / nrm;
    __syncthreads();
    for (int it = 0; it < 3; ++it) {
      float a2 = 0.f;
      const int k0 = h * 64;
      #pragma unroll 8
      for (int k = k0; k < k0 + 64; ++k) a2 += MA[k*DIM + i] * sx[k];
      sf[t] = a2;
      __syncthreads();
      if (h == 0) sy[i] = sf[i] + sf[i+256] + sf[i+512] + sf[i+768];
      __syncthreads();
      sf[t] = (t < DIM) ? sy[t]*sy[t] : 0.f;
      __syncthreads();
      for (int s = 512; s > 0; s >>= 1) {
        if (t < s) sf[t] += sf[t+s];
        __syncthreads();
      }
      const float innrm = rsqrtf(fmaxf(sf[0], 1e-30f));
      __syncthreads();
      if (t < DIM) sx[t] = sy[t] * innrm;
      __syncthreads();
    }
    if (t < DIM) vfin[t] = sx[t];
  }
}

// ---------- projection out = g - (g.v) v (2048 x 256, 2-deep) ----------
__global__ __launch_bounds__(NT_P) void k_project(const float4* __restrict__ g4,
                                                  const float* __restrict__ v,
                                                  float4* __restrict__ out) {
  const int lane = threadIdx.x & 63;
  const float4 v4 = ((const float4*)v)[lane];
  const int w = blockIdx.x * (NT_P/64) + (threadIdx.x >> 6);
  int r = w;
  for (; r + TOTW_P < N_ROWS; r += 2*TOTW_P) {
    float4 a = g4[(size_t)r*64 + lane];
    float4 c = g4[(size_t)(r+TOTW_P)*64 + lane];
    float da = a.x*v4.x + a.y*v4.y + a.z*v4.z + a.w*v4.w;
    float db = c.x*v4.x + c.y*v4.y + c.z*v4.z + c.w*v4.w;
    #pragma unroll
    for (int m = 1; m < 64; m <<= 1) { da += __shfl_xor(da, m, 64); db += __shfl_xor(db, m, 64); }
    out[(size_t)r*64 + lane] = make_float4(a.x-da*v4.x, a.y-da*v4.y, a.z-da*v4.z, a.w-da*v4.w);
    out[(size_t)(r+TOTW_P)*64 + lane] = make_float4(c.x-db*v4.x, c.y-db*v4.y, c.z-db*v4.z, c.w-db*v4.w);
  }
  for (; r < N_ROWS; r += TOTW_P) {
    float4 a = g4[(size_t)r*64 + lane];
    float da = a.x*v4.x + a.y*v4.y + a.z*v4.z + a.w*v4.w;
    #pragma unroll
    for (int m = 1; m < 64; m <<= 1) da += __shfl_xor(da, m, 64);
    out[(size_t)r*64 + lane] = make_float4(a.x-da*v4.x, a.y-da*v4.y, a.z-da*v4.z, a.w-da*v4.w);
  }
}

extern "C" void kernel_launch(void* const* d_in, const int* in_sizes, int n_in,
                              void* d_out, int out_size, void* d_ws, size_t ws_size,
                              hipStream_t stream) {
  const float* grads     = (const float*)d_in[0];
  const int*   labels    = (const int*)d_in[1];
  const float* centroids = (const float*)d_in[2];
  float* out = (float*)d_out;
  char* ws = (char*)d_ws;

  unsigned* idx    = (unsigned*)(ws + OFF_IDX);
  unsigned* counts = (unsigned*)(ws + OFF_COUNTS);
  unsigned* base   = (unsigned*)(ws + OFF_BASE);
  float*    colsum = (float*)(ws + OFF_COLSUM);
  float*    vfin   = (float*)(ws + OFF_V);
  float*    NC     = (float*)(ws + OFF_NC);

  // zero barrier counters + atomic targets every call (graph-replay safe)
  hipMemsetAsync(ws, 0, ZERO_BYTES, stream);

  k_sort<<<NB_S, NT_S, 0, stream>>>(labels, ws);
  k_reduce<<<NCLS, 512, 0, stream>>>(grads, idx, base, counts, centroids, NC, colsum);
  k_eigen<<<NBE, NTE, 0, stream>>>(ws);
  k_project<<<NB_P, NT_P, 0, stream>>>((const float4*)grads, vfin, (float4*)out);
}

// Round 6
// 528.640 us; speedup vs baseline: 1.7401x; 1.2948x over previous
//
#include <hip/hip_runtime.h>

#define N_ROWS 400000
#define DIM 256
#define NCLS 1000
#define NSQ 10

#define NB_S 256      // k_sort blocks
#define NT_S 512
#define NBE  128      // k_eigen blocks (two Gram columns each)
#define NTE  1024
#define NB_P 2048     // k_project blocks
#define NT_P 256
#define TOTW_P (NB_P * (NT_P / 64))   // 8192 waves

// ---- workspace layout (bytes) ----
#define OFF_BAR     0                 // k_sort barrier counter
#define OFF_BAR2    64                // k_eigen barrier counter
#define OFF_COUNTS  1024              // 1024 u32
#define OFF_COLSUM  5120              // 256 f32
#define OFF_MAXBUF  6144              // 16 u32
#define ZERO_BYTES  6208
#define OFF_BASE    6208              // 1024 u32
#define OFF_CURSOR  10304             // 1024 u32
#define OFF_V       14400             // 256 f32
#define OFF_IDX     15424             // 400000 u32
#define OFF_NC      1615424           // [NCLS][DIM] f32
#define OFF_MA      2639424           // 256 KB
#define OFF_MB      2901568           // 256 KB

// grid barrier: RELAXED spin (no per-poll L2 invalidate!), one fence on exit.
// counter zeroed by the memset at the head of every kernel_launch call.
template <int NBLK>
__device__ __forceinline__ void grid_bar(unsigned* bar, int& phase) {
  __syncthreads();
  if (threadIdx.x == 0) {
    ++phase;
    __threadfence();   // release: wait stores, write back L2
    __hip_atomic_fetch_add(bar, 1u, __ATOMIC_RELAXED, __HIP_MEMORY_SCOPE_AGENT);
    const unsigned target = (unsigned)NBLK * (unsigned)phase;
    while (__hip_atomic_load(bar, __ATOMIC_RELAXED, __HIP_MEMORY_SCOPE_AGENT) < target)
      __builtin_amdgcn_s_sleep(8);
    __threadfence();   // acquire: invalidate stale lines ONCE
  }
  __syncthreads();
}

// ---------- counting sort of row indices (hist -> scan -> scatter) ----------
__global__ __launch_bounds__(NT_S) void k_sort(const int* __restrict__ labels,
                                               char* __restrict__ ws) {
  unsigned* bar    = (unsigned*)(ws + OFF_BAR);
  unsigned* counts = (unsigned*)(ws + OFF_COUNTS);
  unsigned* base   = (unsigned*)(ws + OFF_BASE);
  unsigned* cursor = (unsigned*)(ws + OFF_CURSOR);
  unsigned* idx    = (unsigned*)(ws + OFF_IDX);

  __shared__ unsigned su[1024];
  const int t = threadIdx.x, b = blockIdx.x;
  int phase = 0;

  // P1: histogram (LDS-private, flush to global)
  for (int i = t; i < NCLS; i += NT_S) su[i] = 0u;
  __syncthreads();
  for (int i = b*NT_S + t; i < N_ROWS; i += NB_S*NT_S)
    atomicAdd(&su[labels[i]], 1u);
  __syncthreads();
  for (int i = t; i < NCLS; i += NT_S) { unsigned v = su[i]; if (v) atomicAdd(&counts[i], v); }
  grid_bar<NB_S>(bar, phase);

  // P2: exclusive scan (block 0, Blelloch over 1024)
  if (b == 0) {
    su[t] = counts[t]; su[t+512] = counts[t+512];
    int offset = 1;
    for (int d = 512; d > 0; d >>= 1) {
      __syncthreads();
      if (t < d) { int ai = offset*(2*t+1)-1, bi = offset*(2*t+2)-1; su[bi] += su[ai]; }
      offset <<= 1;
    }
    __syncthreads();
    if (t == 0) su[1023] = 0u;
    for (int d = 1; d < 1024; d <<= 1) {
      offset >>= 1;
      __syncthreads();
      if (t < d) { int ai = offset*(2*t+1)-1, bi = offset*(2*t+2)-1;
                   unsigned tm = su[ai]; su[ai] = su[bi]; su[bi] += tm; }
    }
    __syncthreads();
    base[t] = su[t]; cursor[t] = su[t];
    base[t+512] = su[t+512]; cursor[t+512] = su[t+512];
  }
  grid_bar<NB_S>(bar, phase);

  // P3: scatter
  for (int i = b*NT_S + t; i < N_ROWS; i += NB_S*NT_S) {
    unsigned p = atomicAdd(&cursor[labels[i]], 1u);
    idx[p] = (unsigned)i;
  }
}

// ---------- per-class gather-mean + EMA -> NC (+ colsum fold) ----------
__global__ __launch_bounds__(512) void k_reduce(const float* __restrict__ grads,
                                                const unsigned* __restrict__ idx,
                                                const unsigned* __restrict__ base,
                                                const unsigned* __restrict__ counts,
                                                const float* __restrict__ centroids,
                                                float* __restrict__ NC,
                                                float* __restrict__ colsum) {
  const int cls = blockIdx.x;
  const unsigned s0 = base[cls], n = counts[cls];
  const int wave = threadIdx.x >> 6, lane = threadIdx.x & 63;
  const float4* g4 = (const float4*)grads;
  float4 acc = make_float4(0.f, 0.f, 0.f, 0.f);
  unsigned u = (unsigned)wave;
  for (; u + 8 < n; u += 16) {                 // 2 rows in flight per wave
    unsigned r0 = idx[s0+u], r1 = idx[s0+u+8];
    float4 a = g4[(size_t)r0*64 + lane];
    float4 c = g4[(size_t)r1*64 + lane];
    acc.x += a.x + c.x; acc.y += a.y + c.y;
    acc.z += a.z + c.z; acc.w += a.w + c.w;
  }
  for (; u < n; u += 8) {
    unsigned r0 = idx[s0+u];
    float4 a = g4[(size_t)r0*64 + lane];
    acc.x += a.x; acc.y += a.y; acc.z += a.z; acc.w += a.w;
  }
  __shared__ float4 tmp[8][64];
  tmp[wave][lane] = acc;
  __syncthreads();
  const int d = threadIdx.x;
  if (d < DIM) {
    const float* tf = (const float*)tmp;
    float s = 0.f;
    #pragma unroll
    for (int w2 = 0; w2 < 8; ++w2) s += tf[w2*256 + d];
    float mean = s / fmaxf((float)n, 1.0f);
    float ce = centroids[cls*DIM + d];
    float ncv = (n > 0u) ? (0.9f*ce + 0.1f*mean) : ce;
    NC[cls*DIM + d] = ncv;
    atomicAdd(&colsum[d], ncv);              // colsum folded here
  }
}

// ---------- eigenvector chain (coop 128 x 1024, 11 grid barriers) ----------
__global__ __launch_bounds__(NTE) void k_eigen(char* __restrict__ ws) {
  unsigned* bar2   = (unsigned*)(ws + OFF_BAR2);
  float*    colsum = (float*)(ws + OFF_COLSUM);
  unsigned* maxbuf = (unsigned*)(ws + OFF_MAXBUF);
  float*    vfin   = (float*)(ws + OFF_V);
  float*    NC     = (float*)(ws + OFF_NC);
  float*    MA     = (float*)(ws + OFF_MA);
  float*    MB     = (float*)(ws + OFF_MB);

  __shared__ float scol[2][NCLS];    // staged columns/rows
  __shared__ float sf[2][NTE];       // k-split partials
  __shared__ float sx[DIM], sy[DIM];
  __shared__ int   sidx[256];
  __shared__ unsigned smax;

  const int t = threadIdx.x, b = blockIdx.x;
  const int i = t & 255, h = t >> 8;           // output row, k-chunk
  int phase = 0;

  // P1: Gram of centered NC, columns j0=b, j1=b+NBE (shared NC loads)
  {
    const int j0 = b, j1 = b + NBE;
    if (t < NCLS) { scol[0][t] = NC[t*DIM + j0]; scol[1][t] = NC[t*DIM + j1]; }
    if (t == 0) smax = 0u;
    __syncthreads();
    float a0 = 0.f, a1 = 0.f;
    const int k0 = h * 250;
    #pragma unroll 5
    for (int k = k0; k < k0 + 250; ++k) {
      float nv = NC[k*DIM + i];
      a0 += nv * scol[0][k];
      a1 += nv * scol[1][k];
    }
    sf[0][t] = a0; sf[1][t] = a1;
    __syncthreads();
    if (h == 0) {
      float v0 = sf[0][i]+sf[0][i+256]+sf[0][i+512]+sf[0][i+768] - colsum[i]*colsum[j0]*(1.0f/NCLS);
      float v1 = sf[1][i]+sf[1][i+256]+sf[1][i+512]+sf[1][i+768] - colsum[i]*colsum[j1]*(1.0f/NCLS);
      MA[j0*DIM + i] = v0;
      MA[j1*DIM + i] = v1;
      float am = fmaxf(fabsf(v0), fabsf(v1));
      #pragma unroll
      for (int m = 1; m < 64; m <<= 1) am = fmaxf(am, __shfl_xor(am, m, 64));
      if ((t & 63) == 0) atomicMax(&smax, __float_as_uint(am));
    }
    __syncthreads();
    if (t == 0) atomicMax(maxbuf, smax);
  }
  grid_bar<NBE>(bar2, phase);

  // P2: NSQ normalized squarings, columns j0=b, j1=b+NBE each step
  for (int st = 0; st < NSQ; ++st) {
    const float* A = (st & 1) ? MB : MA;
    float*       C = (st & 1) ? MA : MB;
    const float inv = 1.0f / __uint_as_float(maxbuf[st]);
    const int j0 = b, j1 = b + NBE;
    if (t < DIM) { scol[0][t] = A[j0*DIM + t]; scol[1][t] = A[j1*DIM + t]; }  // rows==cols (sym)
    if (t == 0) smax = 0u;
    __syncthreads();
    float a0 = 0.f, a1 = 0.f;
    const int k0 = h * 64;
    #pragma unroll 8
    for (int k = k0; k < k0 + 64; ++k) {
      float av = A[k*DIM + i];
      a0 += av * scol[0][k];
      a1 += av * scol[1][k];
    }
    sf[0][t] = a0; sf[1][t] = a1;
    __syncthreads();
    if (h == 0) {
      float v0 = (sf[0][i]+sf[0][i+256]+sf[0][i+512]+sf[0][i+768]) * inv * inv;
      float v1 = (sf[1][i]+sf[1][i+256]+sf[1][i+512]+sf[1][i+768]) * inv * inv;
      C[j0*DIM + i] = v0;
      C[j1*DIM + i] = v1;
      float am = fmaxf(fabsf(v0), fabsf(v1));
      #pragma unroll
      for (int m = 1; m < 64; m <<= 1) am = fmaxf(am, __shfl_xor(am, m, 64));
      if ((t & 63) == 0) atomicMax(&smax, __float_as_uint(am));
    }
    __syncthreads();
    if (t == 0) atomicMax(&maxbuf[st+1], smax);
    grid_bar<NBE>(bar2, phase);
  }
  // NSQ even -> final matrix in MA

  // P3: pickcol + 3 power-polish iterations, block 0 only
  if (b == 0) {
    const int k0 = h * 64;
    float ns = 0.f;
    for (int k = k0; k < k0 + 64; ++k) { float x = MA[k*DIM + i]; ns += x*x; }
    sf[0][t] = ns;
    __syncthreads();
    if (h == 0) {
      scol[0][i] = sf[0][i]+sf[0][i+256]+sf[0][i+512]+sf[0][i+768];
      sidx[i] = i;
    }
    __syncthreads();
    for (int s = 128; s > 0; s >>= 1) {
      if (t < s && scol[0][t+s] > scol[0][t]) { scol[0][t] = scol[0][t+s]; sidx[t] = sidx[t+s]; }
      __syncthreads();
    }
    const int jm = sidx[0];
    const float nrm = sqrtf(fmaxf(scol[0][0], 1e-30f));
    __syncthreads();
    if (t < DIM) sx[t] = MA[(size_t)jm*DIM + t] / nrm;
    __syncthreads();
    for (int it = 0; it < 3; ++it) {
      float a2 = 0.f;
      #pragma unroll 8
      for (int k = k0; k < k0 + 64; ++k) a2 += MA[k*DIM + i] * sx[k];
      sf[0][t] = a2;
      __syncthreads();
      if (h == 0) {
        float yv = sf[0][i]+sf[0][i+256]+sf[0][i+512]+sf[0][i+768];
        sy[i] = yv;
        float q = yv*yv;
        #pragma unroll
        for (int m = 1; m < 64; m <<= 1) q += __shfl_xor(q, m, 64);
        if ((i & 63) == 0) scol[0][i >> 6] = q;
      }
      __syncthreads();
      const float innrm = rsqrtf(fmaxf(scol[0][0]+scol[0][1]+scol[0][2]+scol[0][3], 1e-30f));
      if (t < DIM) sx[t] = sy[t] * innrm;
      __syncthreads();
    }
    if (t < DIM) vfin[t] = sx[t];
  }
}

// ---------- projection out = g - (g.v) v (2048 x 256, 2-deep) ----------
__global__ __launch_bounds__(NT_P) void k_project(const float4* __restrict__ g4,
                                                  const float* __restrict__ v,
                                                  float4* __restrict__ out) {
  const int lane = threadIdx.x & 63;
  const float4 v4 = ((const float4*)v)[lane];
  const int w = blockIdx.x * (NT_P/64) + (threadIdx.x >> 6);
  int r = w;
  for (; r + TOTW_P < N_ROWS; r += 2*TOTW_P) {
    float4 a = g4[(size_t)r*64 + lane];
    float4 c = g4[(size_t)(r+TOTW_P)*64 + lane];
    float da = a.x*v4.x + a.y*v4.y + a.z*v4.z + a.w*v4.w;
    float db = c.x*v4.x + c.y*v4.y + c.z*v4.z + c.w*v4.w;
    #pragma unroll
    for (int m = 1; m < 64; m <<= 1) { da += __shfl_xor(da, m, 64); db += __shfl_xor(db, m, 64); }
    out[(size_t)r*64 + lane] = make_float4(a.x-da*v4.x, a.y-da*v4.y, a.z-da*v4.z, a.w-da*v4.w);
    out[(size_t)(r+TOTW_P)*64 + lane] = make_float4(c.x-db*v4.x, c.y-db*v4.y, c.z-db*v4.z, c.w-db*v4.w);
  }
  for (; r < N_ROWS; r += TOTW_P) {
    float4 a = g4[(size_t)r*64 + lane];
    float da = a.x*v4.x + a.y*v4.y + a.z*v4.z + a.w*v4.w;
    #pragma unroll
    for (int m = 1; m < 64; m <<= 1) da += __shfl_xor(da, m, 64);
    out[(size_t)r*64 + lane] = make_float4(a.x-da*v4.x, a.y-da*v4.y, a.z-da*v4.z, a.w-da*v4.w);
  }
}

extern "C" void kernel_launch(void* const* d_in, const int* in_sizes, int n_in,
                              void* d_out, int out_size, void* d_ws, size_t ws_size,
                              hipStream_t stream) {
  const float* grads     = (const float*)d_in[0];
  const int*   labels    = (const int*)d_in[1];
  const float* centroids = (const float*)d_in[2];
  float* out = (float*)d_out;
  char* ws = (char*)d_ws;

  unsigned* idx    = (unsigned*)(ws + OFF_IDX);
  unsigned* counts = (unsigned*)(ws + OFF_COUNTS);
  unsigned* base   = (unsigned*)(ws + OFF_BASE);
  float*    colsum = (float*)(ws + OFF_COLSUM);
  float*    vfin   = (float*)(ws + OFF_V);
  float*    NC     = (float*)(ws + OFF_NC);

  // zero barrier counters + atomic targets every call (graph-replay safe)
  hipMemsetAsync(ws, 0, ZERO_BYTES, stream);

  k_sort<<<NB_S, NT_S, 0, stream>>>(labels, ws);
  k_reduce<<<NCLS, 512, 0, stream>>>(grads, idx, base, counts, centroids, NC, colsum);
  k_eigen<<<NBE, NTE, 0, stream>>>(ws);
  k_project<<<NB_P, NT_P, 0, stream>>>((const float4*)grads, vfin, (float4*)out);
}

// Round 8
// 440.077 us; speedup vs baseline: 2.0903x; 1.2012x over previous
//
#include <hip/hip_runtime.h>

#define N_ROWS 400000
#define DIM 256
#define NCLS 1000
#define NSQ 8

#define NB_S 256      // k_sort blocks
#define NT_S 512
#define NBE  64       // k_eigen blocks (four Gram columns each)
#define NTE  1024
#define NB_P 2048     // k_project blocks
#define NT_P 256
#define TOTW_P (NB_P * (NT_P / 64))   // 8192 waves

typedef float f4 __attribute__((ext_vector_type(4)));   // native vec for nontemporal builtins

// ---- workspace layout (bytes) ----
#define OFF_BAR     0                 // k_sort barrier counter
#define OFF_BAR2    64                // k_eigen barrier counter
#define OFF_COUNTS  1024              // 1024 u32
#define OFF_COLSUM  5120              // 256 f32
#define OFF_MAXBUF  6144              // 16 u32
#define ZERO_BYTES  6208
#define OFF_BASE    6208              // 1024 u32
#define OFF_CURSOR  10304             // 1024 u32
#define OFF_V       14400             // 256 f32
#define OFF_IDX     15424             // 400000 u32
#define OFF_NC      1615424           // [NCLS][DIM] f32
#define OFF_NCT     2639424           // [DIM][NCLS] f32 (transposed)
#define OFF_MA      3663424           // 256 KB
#define OFF_MB      3925568           // 256 KB

// grid barrier: RELAXED spin, one fence on exit. counter zeroed per call.
template <int NBLK>
__device__ __forceinline__ void grid_bar(unsigned* bar, int& phase) {
  __syncthreads();
  if (threadIdx.x == 0) {
    ++phase;
    __threadfence();   // release
    __hip_atomic_fetch_add(bar, 1u, __ATOMIC_RELAXED, __HIP_MEMORY_SCOPE_AGENT);
    const unsigned target = (unsigned)NBLK * (unsigned)phase;
    while (__hip_atomic_load(bar, __ATOMIC_RELAXED, __HIP_MEMORY_SCOPE_AGENT) < target)
      __builtin_amdgcn_s_sleep(8);
    __threadfence();   // acquire
  }
  __syncthreads();
}

// ---------- counting sort of row indices (hist -> scan -> scatter) ----------
__global__ __launch_bounds__(NT_S) void k_sort(const int* __restrict__ labels,
                                               char* __restrict__ ws) {
  unsigned* bar    = (unsigned*)(ws + OFF_BAR);
  unsigned* counts = (unsigned*)(ws + OFF_COUNTS);
  unsigned* base   = (unsigned*)(ws + OFF_BASE);
  unsigned* cursor = (unsigned*)(ws + OFF_CURSOR);
  unsigned* idx    = (unsigned*)(ws + OFF_IDX);

  __shared__ unsigned su[1024];
  const int t = threadIdx.x, b = blockIdx.x;
  int phase = 0;

  for (int i = t; i < NCLS; i += NT_S) su[i] = 0u;
  __syncthreads();
  for (int i = b*NT_S + t; i < N_ROWS; i += NB_S*NT_S)
    atomicAdd(&su[labels[i]], 1u);
  __syncthreads();
  for (int i = t; i < NCLS; i += NT_S) { unsigned v = su[i]; if (v) atomicAdd(&counts[i], v); }
  grid_bar<NB_S>(bar, phase);

  if (b == 0) {
    su[t] = counts[t]; su[t+512] = counts[t+512];
    int offset = 1;
    for (int d = 512; d > 0; d >>= 1) {
      __syncthreads();
      if (t < d) { int ai = offset*(2*t+1)-1, bi = offset*(2*t+2)-1; su[bi] += su[ai]; }
      offset <<= 1;
    }
    __syncthreads();
    if (t == 0) su[1023] = 0u;
    for (int d = 1; d < 1024; d <<= 1) {
      offset >>= 1;
      __syncthreads();
      if (t < d) { int ai = offset*(2*t+1)-1, bi = offset*(2*t+2)-1;
                   unsigned tm = su[ai]; su[ai] = su[bi]; su[bi] += tm; }
    }
    __syncthreads();
    base[t] = su[t]; cursor[t] = su[t];
    base[t+512] = su[t+512]; cursor[t+512] = su[t+512];
  }
  grid_bar<NB_S>(bar, phase);

  for (int i = b*NT_S + t; i < N_ROWS; i += NB_S*NT_S) {
    unsigned p = atomicAdd(&cursor[labels[i]], 1u);
    idx[p] = (unsigned)i;
  }
}

// ---------- per-class gather-mean + EMA -> NC, NCT, colsum ----------
__global__ __launch_bounds__(512) void k_reduce(const float* __restrict__ grads,
                                                const unsigned* __restrict__ idx,
                                                const unsigned* __restrict__ base,
                                                const unsigned* __restrict__ counts,
                                                const float* __restrict__ centroids,
                                                float* __restrict__ NC,
                                                float* __restrict__ NCT,
                                                float* __restrict__ colsum) {
  const int cls = blockIdx.x;
  const unsigned s0 = base[cls], n = counts[cls];
  const int wave = threadIdx.x >> 6, lane = threadIdx.x & 63;
  const float4* g4 = (const float4*)grads;
  float4 acc = make_float4(0.f, 0.f, 0.f, 0.f);
  unsigned u = (unsigned)wave;
  for (; u + 24 < n; u += 32) {               // 4 rows in flight per wave
    unsigned r0 = idx[s0+u],    r1 = idx[s0+u+8];
    unsigned r2 = idx[s0+u+16], r3 = idx[s0+u+24];
    float4 a = g4[(size_t)r0*64 + lane];
    float4 c = g4[(size_t)r1*64 + lane];
    float4 d = g4[(size_t)r2*64 + lane];
    float4 e = g4[(size_t)r3*64 + lane];
    acc.x += (a.x + c.x) + (d.x + e.x);
    acc.y += (a.y + c.y) + (d.y + e.y);
    acc.z += (a.z + c.z) + (d.z + e.z);
    acc.w += (a.w + c.w) + (d.w + e.w);
  }
  for (; u < n; u += 8) {
    unsigned r0 = idx[s0+u];
    float4 a = g4[(size_t)r0*64 + lane];
    acc.x += a.x; acc.y += a.y; acc.z += a.z; acc.w += a.w;
  }
  __shared__ float4 tmp[8][64];
  tmp[wave][lane] = acc;
  __syncthreads();
  const int d = threadIdx.x;
  if (d < DIM) {
    const float* tf = (const float*)tmp;
    float s = 0.f;
    #pragma unroll
    for (int w2 = 0; w2 < 8; ++w2) s += tf[w2*256 + d];
    float mean = s / fmaxf((float)n, 1.0f);
    float ce = centroids[cls*DIM + d];
    float ncv = (n > 0u) ? (0.9f*ce + 0.1f*mean) : ce;
    NC[cls*DIM + d]  = ncv;
    NCT[d*NCLS + cls] = ncv;                 // transposed copy for eigen
    atomicAdd(&colsum[d], ncv);
  }
}

// ---------- eigenvector chain (coop 64 x 1024, 9 grid barriers) ----------
__global__ __launch_bounds__(NTE) void k_eigen(char* __restrict__ ws) {
  unsigned* bar2   = (unsigned*)(ws + OFF_BAR2);
  float*    colsum = (float*)(ws + OFF_COLSUM);
  unsigned* maxbuf = (unsigned*)(ws + OFF_MAXBUF);
  float*    vfin   = (float*)(ws + OFF_V);
  float*    NC     = (float*)(ws + OFF_NC);
  float*    NCT    = (float*)(ws + OFF_NCT);
  float*    MA     = (float*)(ws + OFF_MA);
  float*    MB     = (float*)(ws + OFF_MB);

  __shared__ float scol[4][NCLS];    // staged columns/rows
  __shared__ float sf[4][NTE];       // k-split partials
  __shared__ float sx[DIM], sy[DIM];
  __shared__ int   sidx[256];
  __shared__ unsigned smax;

  const int t = threadIdx.x, b = blockIdx.x;
  const int i = t & 255, h = t >> 8;           // output row, k-chunk (0..3)
  int phase = 0;

  // P1: Gram of centered NC, columns j = b + 64q (coalesced via NCT)
  {
    #pragma unroll
    for (int q = 0; q < 4; ++q)
      if (t < NCLS) scol[q][t] = NCT[(size_t)(b + 64*q)*NCLS + t];
    if (t == 0) smax = 0u;
    __syncthreads();
    float a0 = 0.f, a1 = 0.f, a2 = 0.f, a3 = 0.f;
    const int k0 = h * 250;
    #pragma unroll 5
    for (int k = k0; k < k0 + 250; ++k) {
      float nv = NC[k*DIM + i];
      a0 += nv * scol[0][k]; a1 += nv * scol[1][k];
      a2 += nv * scol[2][k]; a3 += nv * scol[3][k];
    }
    sf[0][t] = a0; sf[1][t] = a1; sf[2][t] = a2; sf[3][t] = a3;
    __syncthreads();
    if (h == 0) {
      float am = 0.f;
      #pragma unroll
      for (int q = 0; q < 4; ++q) {
        const int j = b + 64*q;
        float v = sf[q][i]+sf[q][i+256]+sf[q][i+512]+sf[q][i+768]
                - colsum[i]*colsum[j]*(1.0f/NCLS);
        MA[j*DIM + i] = v;
        am = fmaxf(am, fabsf(v));
      }
      #pragma unroll
      for (int m = 1; m < 64; m <<= 1) am = fmaxf(am, __shfl_xor(am, m, 64));
      if ((t & 63) == 0) atomicMax(&smax, __float_as_uint(am));
    }
    __syncthreads();
    if (t == 0) atomicMax(maxbuf, smax);
  }
  grid_bar<NBE>(bar2, phase);

  // P2: NSQ normalized squarings, columns j = b + 64q each step
  for (int st = 0; st < NSQ; ++st) {
    const float* A = (st & 1) ? MB : MA;
    float*       C = (st & 1) ? MA : MB;
    const float inv = 1.0f / __uint_as_float(maxbuf[st]);
    #pragma unroll
    for (int q = 0; q < 4; ++q)
      if (t < DIM) scol[q][t] = A[(b + 64*q)*DIM + t];   // rows==cols (sym)
    if (t == 0) smax = 0u;
    __syncthreads();
    float a0 = 0.f, a1 = 0.f, a2 = 0.f, a3 = 0.f;
    const int k0 = h * 64;
    #pragma unroll 8
    for (int k = k0; k < k0 + 64; ++k) {
      float av = A[k*DIM + i];
      a0 += av * scol[0][k]; a1 += av * scol[1][k];
      a2 += av * scol[2][k]; a3 += av * scol[3][k];
    }
    sf[0][t] = a0; sf[1][t] = a1; sf[2][t] = a2; sf[3][t] = a3;
    __syncthreads();
    if (h == 0) {
      float am = 0.f;
      #pragma unroll
      for (int q = 0; q < 4; ++q) {
        const int j = b + 64*q;
        float v = (sf[q][i]+sf[q][i+256]+sf[q][i+512]+sf[q][i+768]) * inv * inv;
        C[j*DIM + i] = v;
        am = fmaxf(am, fabsf(v));
      }
      #pragma unroll
      for (int m = 1; m < 64; m <<= 1) am = fmaxf(am, __shfl_xor(am, m, 64));
      if ((t & 63) == 0) atomicMax(&smax, __float_as_uint(am));
    }
    __syncthreads();
    if (t == 0) atomicMax(&maxbuf[st+1], smax);
    grid_bar<NBE>(bar2, phase);
  }
  // NSQ even -> final matrix in MA

  // P3: pickcol + 3 power-polish iterations, block 0 only
  if (b == 0) {
    const int k0 = h * 64;
    float ns = 0.f;
    for (int k = k0; k < k0 + 64; ++k) { float x = MA[k*DIM + i]; ns += x*x; }
    sf[0][t] = ns;
    __syncthreads();
    if (h == 0) {
      scol[0][i] = sf[0][i]+sf[0][i+256]+sf[0][i+512]+sf[0][i+768];
      sidx[i] = i;
    }
    __syncthreads();
    for (int s = 128; s > 0; s >>= 1) {
      if (t < s && scol[0][t+s] > scol[0][t]) { scol[0][t] = scol[0][t+s]; sidx[t] = sidx[t+s]; }
      __syncthreads();
    }
    const int jm = sidx[0];
    const float nrm = sqrtf(fmaxf(scol[0][0], 1e-30f));
    __syncthreads();
    if (t < DIM) sx[t] = MA[(size_t)jm*DIM + t] / nrm;
    __syncthreads();
    for (int it = 0; it < 3; ++it) {
      float a2 = 0.f;
      #pragma unroll 8
      for (int k = k0; k < k0 + 64; ++k) a2 += MA[k*DIM + i] * sx[k];
      sf[0][t] = a2;
      __syncthreads();
      if (h == 0) {
        float yv = sf[0][i]+sf[0][i+256]+sf[0][i+512]+sf[0][i+768];
        sy[i] = yv;
        float q = yv*yv;
        #pragma unroll
        for (int m = 1; m < 64; m <<= 1) q += __shfl_xor(q, m, 64);
        if ((i & 63) == 0) scol[0][i >> 6] = q;
      }
      __syncthreads();
      const float innrm = rsqrtf(fmaxf(scol[0][0]+scol[0][1]+scol[0][2]+scol[0][3], 1e-30f));
      if (t < DIM) sx[t] = sy[t] * innrm;
      __syncthreads();
    }
    if (t < DIM) vfin[t] = sx[t];
  }
}

// ---------- projection out = g - (g.v) v (nontemporal streaming) ----------
__global__ __launch_bounds__(NT_P) void k_project(const f4* __restrict__ g4,
                                                  const float* __restrict__ v,
                                                  f4* __restrict__ out) {
  const int lane = threadIdx.x & 63;
  const f4 v4 = ((const f4*)v)[lane];
  const int w = blockIdx.x * (NT_P/64) + (threadIdx.x >> 6);
  int r = w;
  for (; r + TOTW_P < N_ROWS; r += 2*TOTW_P) {
    f4 a = __builtin_nontemporal_load(&g4[(size_t)r*64 + lane]);
    f4 c = __builtin_nontemporal_load(&g4[(size_t)(r+TOTW_P)*64 + lane]);
    float da = a.x*v4.x + a.y*v4.y + a.z*v4.z + a.w*v4.w;
    float db = c.x*v4.x + c.y*v4.y + c.z*v4.z + c.w*v4.w;
    #pragma unroll
    for (int m = 1; m < 64; m <<= 1) { da += __shfl_xor(da, m, 64); db += __shfl_xor(db, m, 64); }
    f4 o0 = a - da * v4;
    f4 o1 = c - db * v4;
    __builtin_nontemporal_store(o0, &out[(size_t)r*64 + lane]);
    __builtin_nontemporal_store(o1, &out[(size_t)(r+TOTW_P)*64 + lane]);
  }
  for (; r < N_ROWS; r += TOTW_P) {
    f4 a = __builtin_nontemporal_load(&g4[(size_t)r*64 + lane]);
    float da = a.x*v4.x + a.y*v4.y + a.z*v4.z + a.w*v4.w;
    #pragma unroll
    for (int m = 1; m < 64; m <<= 1) da += __shfl_xor(da, m, 64);
    f4 o = a - da * v4;
    __builtin_nontemporal_store(o, &out[(size_t)r*64 + lane]);
  }
}

extern "C" void kernel_launch(void* const* d_in, const int* in_sizes, int n_in,
                              void* d_out, int out_size, void* d_ws, size_t ws_size,
                              hipStream_t stream) {
  const float* grads     = (const float*)d_in[0];
  const int*   labels    = (const int*)d_in[1];
  const float* centroids = (const float*)d_in[2];
  float* out = (float*)d_out;
  char* ws = (char*)d_ws;

  unsigned* idx    = (unsigned*)(ws + OFF_IDX);
  unsigned* counts = (unsigned*)(ws + OFF_COUNTS);
  unsigned* base   = (unsigned*)(ws + OFF_BASE);
  float*    colsum = (float*)(ws + OFF_COLSUM);
  float*    vfin   = (float*)(ws + OFF_V);
  float*    NC     = (float*)(ws + OFF_NC);
  float*    NCT    = (float*)(ws + OFF_NCT);

  (void)hipMemsetAsync(ws, 0, ZERO_BYTES, stream);

  k_sort<<<NB_S, NT_S, 0, stream>>>(labels, ws);
  k_reduce<<<NCLS, 512, 0, stream>>>(grads, idx, base, counts, centroids, NC, NCT, colsum);
  k_eigen<<<NBE, NTE, 0, stream>>>(ws);
  k_project<<<NB_P, NT_P, 0, stream>>>((const f4*)grads, vfin, (f4*)out);
}